// Round 4
// baseline (155.165 us; speedup 1.0000x reference)
//
#include <hip/hip_runtime.h>
#include <hip/hip_bf16.h>

// LIF: V = V + (I - V)/tau; spike = V >= 1.0; V = spike ? 0 : V
// d_out = [spike_trace (0/1 f32) | voltage_trace (f32)], each T*B*N.
//
// Memory-bound streaming: 268 MB read + 537 MB write, zero reuse.
// R3 = R2 with clang ext_vector float4 (HIP_vector_type float4 is rejected
// by __builtin_nontemporal_*; a true clang vector type is accepted).
// - float4 (16B/lane) loads AND stores -> dwordx4, m13's 6.29 TB/s regime.
// - block=64, grid=512: 2 blocks/CU across ALL 256 CUs / 8 XCDs evenly.
// - UNROLL=8 float4 loads in flight per wave.
// - Nontemporal loads/stores (pure streaming, no reuse).

#define LIF_T 512
#define V_TH 1.0f
#define TAU 20.0f
#define UNROLL 8

typedef float f32x4 __attribute__((ext_vector_type(4)));

__global__ __launch_bounds__(64) void lif_kernel(const f32x4* __restrict__ in,
                                                 f32x4* __restrict__ spikes,
                                                 f32x4* __restrict__ volts,
                                                 int BN4) {
    const int i = blockIdx.x * blockDim.x + threadIdx.x;
    if (i >= BN4) return;

    f32x4 V = (f32x4)(0.0f);
    size_t off = (size_t)i;
    const size_t stride = (size_t)BN4;

    for (int t = 0; t < LIF_T; t += UNROLL) {
        // Batch-issue UNROLL independent 16B loads.
        f32x4 Iv[UNROLL];
        #pragma unroll
        for (int u = 0; u < UNROLL; ++u)
            Iv[u] = __builtin_nontemporal_load(&in[off + (size_t)u * stride]);

        #pragma unroll
        for (int u = 0; u < UNROLL; ++u) {
            const size_t o = off + (size_t)u * stride;
            f32x4 sp;
            // EXACT reference op order per component: sub, IEEE div 20.0f, add.
            #pragma unroll
            for (int c = 0; c < 4; ++c) {
                float v = V[c];
                v = v + (Iv[u][c] - v) / TAU;
                const bool s = (v >= V_TH);
                sp[c] = s ? 1.0f : 0.0f;
                V[c] = s ? 0.0f : v;
            }
            __builtin_nontemporal_store(sp, &spikes[o]);
            __builtin_nontemporal_store(V, &volts[o]);
        }
        off += (size_t)UNROLL * stride;
    }
}

extern "C" void kernel_launch(void* const* d_in, const int* in_sizes, int n_in,
                              void* d_out, int out_size, void* d_ws, size_t ws_size,
                              hipStream_t stream) {
    const float* in = (const float*)d_in[0];
    float* out = (float*)d_out;

    const int total = in_sizes[0];          // T*B*N
    const int BN = total / LIF_T;           // 131072
    const int BN4 = BN / 4;                 // 32768 float4 lanes

    float* spikes = out;                     // first T*B*N floats
    float* volts  = out + (size_t)total;     // second T*B*N floats

    const int block = 64;
    const int grid = (BN4 + block - 1) / block;  // 512 blocks
    lif_kernel<<<grid, block, 0, stream>>>((const f32x4*)in,
                                           (f32x4*)spikes,
                                           (f32x4*)volts, BN4);
}